// Round 2
// baseline (2658.990 us; speedup 1.0000x reference)
//
#include <hip/hip_runtime.h>

#define N_NODES 50000
#define N_EDGES 800000
#define C_IN    128
#define C_HID   256
#define C_OUT   128
#define SEG_STRIDE 132   // col 0: edge_attr sum, 1..128: z_src sum, 129: count, 130-131: pad(0)

// ws layout: [seg: N*132 f32][Wa1p: 132*256 f32]

__global__ void prep_wa1(const float* __restrict__ Wa1, float* __restrict__ Wa1p) {
    int t = blockIdx.x * 256 + threadIdx.x;
    if (t >= 132 * 256) return;
    int k = t >> 8, c = t & 255;
    Wa1p[t] = (k < (C_IN + 1)) ? Wa1[k * C_HID + c] : 0.0f;
}

// One block = 32 edges. Stages [z_src|z_dst] (32x256 f32) in LDS, fuses:
//  (a) scatter-add of [edge_attr, z_src] + count into seg (atomics)
//  (b) edge MLP layer1 (thread = hid channel, 32 edge accumulators)
//  (c) relu + dot with We2 via wave shuffle reduce -> edge_recon
__global__ __launch_bounds__(256) void edge_kernel(
    const float* __restrict__ z, const int* __restrict__ ei,
    const float* __restrict__ eattr,
    const float* __restrict__ We1, const float* __restrict__ be1,
    const float* __restrict__ We2, const float* __restrict__ be2,
    float* __restrict__ seg, float* __restrict__ edge_out)
{
    __shared__ float s_in[32][256];
    __shared__ float s_w2[256];
    __shared__ float s_red[4][32];
    const int tid = threadIdx.x;
    const long long e0 = (long long)blockIdx.x * 32;

    s_w2[tid] = We2[tid];

    for (int ee = 0; ee < 32; ++ee) {
        const long long e = e0 + ee;
        const int s = ei[e];              // int32 per harness contract
        const int d = ei[N_EDGES + e];
        if (tid < 128) {
            const float v = z[(long long)s * C_IN + tid];
            s_in[ee][tid] = v;
            atomicAdd(&seg[(long long)d * SEG_STRIDE + 1 + tid], v);
        } else {
            s_in[ee][tid] = z[(long long)d * C_IN + (tid - 128)];
            if (tid == 128) atomicAdd(&seg[(long long)d * SEG_STRIDE], eattr[e]);
            if (tid == 129) atomicAdd(&seg[(long long)d * SEG_STRIDE + 129], 1.0f);
        }
    }
    __syncthreads();

    const int c = tid;  // hid channel
    float acc[32];
    #pragma unroll
    for (int ee = 0; ee < 32; ++ee) acc[ee] = 0.0f;

    for (int k4 = 0; k4 < 64; ++k4) {
        const float w0 = We1[(k4 * 4 + 0) * C_HID + c];
        const float w1 = We1[(k4 * 4 + 1) * C_HID + c];
        const float w2 = We1[(k4 * 4 + 2) * C_HID + c];
        const float w3 = We1[(k4 * 4 + 3) * C_HID + c];
        #pragma unroll
        for (int ee = 0; ee < 32; ++ee) {
            const float4 x = *(const float4*)&s_in[ee][k4 * 4];  // broadcast b128
            acc[ee] += x.x * w0 + x.y * w1 + x.z * w2 + x.w * w3;
        }
    }

    const float b1  = be1[c];
    const float w2c = s_w2[c];
    const int wid  = tid >> 6;
    const int lane = tid & 63;
    #pragma unroll
    for (int ee = 0; ee < 32; ++ee) {
        float v = fmaxf(acc[ee] + b1, 0.0f) * w2c;
        #pragma unroll
        for (int off = 32; off >= 1; off >>= 1) v += __shfl_xor(v, off, 64);
        if (lane == 0) s_red[wid][ee] = v;
    }
    __syncthreads();
    if (tid < 32) {
        const float r = s_red[0][tid] + s_red[1][tid] + s_red[2][tid] + s_red[3][tid];
        edge_out[e0 + tid] = r + be2[0];
    }
}

__global__ void normalize_kernel(float* __restrict__ seg) {
    const long long t = (long long)blockIdx.x * 256 + threadIdx.x;
    if (t >= (long long)N_NODES * 129) return;
    const int n = (int)(t / 129);
    const int k = (int)(t % 129);
    const float cnt = seg[n * SEG_STRIDE + 129];
    const float v   = seg[n * SEG_STRIDE + k];
    seg[n * SEG_STRIDE + k] = (cnt > 0.0f) ? v / cnt : 0.0f;
}

// One block = 16 nodes. K padded to 132: rows 129..131 of Wa1p are zero, so the
// count column (129) in s_in contributes exactly 0.
__global__ __launch_bounds__(256) void node_kernel(
    const float* __restrict__ seg, const float* __restrict__ Wa1p,
    const float* __restrict__ ba1, const float* __restrict__ Wa2,
    const float* __restrict__ ba2, float* __restrict__ x_out)
{
    __shared__ float s_in[16][132];
    __shared__ float s_h[16][256];
    const int tid = threadIdx.x;
    const long long n0 = (long long)blockIdx.x * 16;

    for (int nn = 0; nn < 16; ++nn) {
        if (tid < 132) s_in[nn][tid] = seg[(n0 + nn) * SEG_STRIDE + tid];
    }
    __syncthreads();

    const int c = tid;
    float acc[16];
    #pragma unroll
    for (int nn = 0; nn < 16; ++nn) acc[nn] = 0.0f;

    for (int k4 = 0; k4 < 33; ++k4) {
        const float w0 = Wa1p[(k4 * 4 + 0) * C_HID + c];
        const float w1 = Wa1p[(k4 * 4 + 1) * C_HID + c];
        const float w2 = Wa1p[(k4 * 4 + 2) * C_HID + c];
        const float w3 = Wa1p[(k4 * 4 + 3) * C_HID + c];
        #pragma unroll
        for (int nn = 0; nn < 16; ++nn) {
            const float4 x = *(const float4*)&s_in[nn][k4 * 4];
            acc[nn] += x.x * w0 + x.y * w1 + x.z * w2 + x.w * w3;
        }
    }
    const float b1 = ba1[c];
    #pragma unroll
    for (int nn = 0; nn < 16; ++nn) s_h[nn][c] = fmaxf(acc[nn] + b1, 0.0f);
    __syncthreads();

    const int j = tid & 127;
    const int g = tid >> 7;  // node half: g*8 .. g*8+7
    float acc2[8];
    #pragma unroll
    for (int nn = 0; nn < 8; ++nn) acc2[nn] = 0.0f;

    for (int k4 = 0; k4 < 64; ++k4) {
        const float w0 = Wa2[(k4 * 4 + 0) * C_OUT + j];
        const float w1 = Wa2[(k4 * 4 + 1) * C_OUT + j];
        const float w2 = Wa2[(k4 * 4 + 2) * C_OUT + j];
        const float w3 = Wa2[(k4 * 4 + 3) * C_OUT + j];
        #pragma unroll
        for (int nn = 0; nn < 8; ++nn) {
            const float4 x = *(const float4*)&s_h[g * 8 + nn][k4 * 4];
            acc2[nn] += x.x * w0 + x.y * w1 + x.z * w2 + x.w * w3;
        }
    }
    const float b2 = ba2[j];
    #pragma unroll
    for (int nn = 0; nn < 8; ++nn)
        x_out[(n0 + g * 8 + nn) * C_OUT + j] = acc2[nn] + b2;
}

extern "C" void kernel_launch(void* const* d_in, const int* in_sizes, int n_in,
                              void* d_out, int out_size, void* d_ws, size_t ws_size,
                              hipStream_t stream) {
    const float* z     = (const float*)d_in[0];
    const int*   ei    = (const int*)d_in[1];     // int32 per harness contract
    const float* eattr = (const float*)d_in[2];
    const float* Wa1   = (const float*)d_in[3];
    const float* ba1   = (const float*)d_in[4];
    const float* Wa2   = (const float*)d_in[5];
    const float* ba2   = (const float*)d_in[6];
    const float* We1   = (const float*)d_in[7];
    const float* be1   = (const float*)d_in[8];
    const float* We2   = (const float*)d_in[9];
    const float* be2   = (const float*)d_in[10];

    float* x_out    = (float*)d_out;
    float* edge_out = x_out + (size_t)N_NODES * C_OUT;

    float* seg  = (float*)d_ws;
    float* Wa1p = seg + (size_t)N_NODES * SEG_STRIDE;

    hipMemsetAsync(seg, 0, (size_t)N_NODES * SEG_STRIDE * sizeof(float), stream);
    prep_wa1<<<132, 256, 0, stream>>>(Wa1, Wa1p);
    edge_kernel<<<N_EDGES / 32, 256, 0, stream>>>(z, ei, eattr, We1, be1, We2, be2,
                                                  seg, edge_out);
    normalize_kernel<<<((long long)N_NODES * 129 + 255) / 256, 256, 0, stream>>>(seg);
    node_kernel<<<N_NODES / 16, 256, 0, stream>>>(seg, Wa1p, ba1, Wa2, ba2, x_out);
}

// Round 3
// 1243.336 us; speedup vs baseline: 2.1386x; 2.1386x over previous
//
#include <hip/hip_runtime.h>

#define N_NODES 50000
#define N_EDGES 800000
#define C_IN    128
#define C_HID   256
#define C_OUT   128
#define SEG_STRIDE 132   // col 0: attr sum, 1..128: z_src sum, 129: count, 130-131: pad
#define SHARDS 8
#define NODES_PER_SHARD 6250   // 8*6250 = 50000
#define SCAT_CHUNK 6400        // 125 chunks * 6400 = 800000

typedef __bf16 bf16x8 __attribute__((ext_vector_type(8)));
typedef float  f32x4  __attribute__((ext_vector_type(4)));

__device__ __forceinline__ unsigned short f2bf(float x) {
    unsigned u = __float_as_uint(x);
    u = (u + 0x7FFF + ((u >> 16) & 1)) >> 16;   // RNE
    return (unsigned short)u;
}

// ---------- prep kernels ----------

__global__ void cast_z(const float* __restrict__ z, unsigned short* __restrict__ zb) {
    int t = blockIdx.x * 256 + threadIdx.x;          // one float4 per thread
    if (t >= N_NODES * C_IN / 4) return;
    float4 v = ((const float4*)z)[t];
    ushort4 o;
    o.x = f2bf(v.x); o.y = f2bf(v.y); o.z = f2bf(v.z); o.w = f2bf(v.w);
    ((ushort4*)zb)[t] = o;
}

// Pack We1 [256 k][256 n] fp32 -> bf16 MFMA B-fragment order:
// Bpack[((ks*16 + nt)*64 + lane)*8 + j] = We1[ks*32 + (lane>>4)*8 + j][nt*16 + (lane&15)]
__global__ void prep_bpack(const float* __restrict__ We1, unsigned short* __restrict__ Bpack) {
    int t = blockIdx.x * 256 + threadIdx.x;          // 8192 lane-slots
    if (t >= 8 * 16 * 64) return;
    int lane = t & 63, nt = (t >> 6) & 15, ks = t >> 10;
    int n  = nt * 16 + (lane & 15);
    int kb = ks * 32 + (lane >> 4) * 8;
    #pragma unroll
    for (int j = 0; j < 8; ++j)
        Bpack[t * 8 + j] = f2bf(We1[(kb + j) * C_HID + n]);
}

__global__ void prep_wa1(const float* __restrict__ Wa1, float* __restrict__ Wa1p) {
    int t = blockIdx.x * 256 + threadIdx.x;
    if (t >= 132 * 256) return;
    int k = t >> 8, c = t & 255;
    Wa1p[t] = (k < (C_IN + 1)) ? Wa1[k * C_HID + c] : 0.0f;
}

// ---------- edge MLP: bf16 MFMA, fused layer2 dot ----------
// Block = 64 edges. Wave w handles N-range [w*64, w*64+64).
__global__ __launch_bounds__(256, 2) void edge_mfma_kernel(
    const unsigned short* __restrict__ zb, const int* __restrict__ ei,
    const unsigned short* __restrict__ Bpack,
    const float* __restrict__ be1, const float* __restrict__ We2,
    const float* __restrict__ be2, float* __restrict__ edge_out)
{
    __shared__ __align__(16) unsigned short s_a[64][264];  // 264 = 256 + 8 pad
    __shared__ float s_red[4][64];
    const int tid  = threadIdx.x;
    const int lane = tid & 63, w = tid >> 6;
    const long long e0 = (long long)blockIdx.x * 64;

    // B fragments for this wave's 4 n-tiles x 8 k-steps, register-resident.
    bf16x8 bfr[8][4];
    {
        const bf16x8* bp = (const bf16x8*)Bpack;
        #pragma unroll
        for (int ks = 0; ks < 8; ++ks)
            #pragma unroll
            for (int nt = 0; nt < 4; ++nt)
                bfr[ks][nt] = bp[(ks * 16 + (w * 4 + nt)) * 64 + lane];
    }

    // Stage A: 64 edges x [z_src | z_dst] bf16. 128 half-rows, 16 lanes x 16B each.
    {
        const int l16 = tid & 15;
        #pragma unroll
        for (int it = 0; it < 8; ++it) {
            int hr   = it * 16 + (tid >> 4);
            int e    = (int)(e0 + (hr >> 1));
            int half = hr & 1;
            int node = half ? ei[N_EDGES + e] : ei[e];
            bf16x8 v = *(const bf16x8*)(zb + (size_t)node * C_IN + l16 * 8);
            *(bf16x8*)&s_a[hr >> 1][half * 128 + l16 * 8] = v;
        }
    }
    __syncthreads();

    f32x4 acc[4][4];
    #pragma unroll
    for (int mt = 0; mt < 4; ++mt)
        #pragma unroll
        for (int nt = 0; nt < 4; ++nt)
            acc[mt][nt] = (f32x4){0.f, 0.f, 0.f, 0.f};

    const int m16 = lane & 15, quad = lane >> 4;
    #pragma unroll
    for (int ks = 0; ks < 8; ++ks) {
        #pragma unroll
        for (int mt = 0; mt < 4; ++mt) {
            bf16x8 a = *(const bf16x8*)&s_a[mt * 16 + m16][ks * 32 + quad * 8];
            #pragma unroll
            for (int nt = 0; nt < 4; ++nt)
                acc[mt][nt] = __builtin_amdgcn_mfma_f32_16x16x32_bf16(
                    a, bfr[ks][nt], acc[mt][nt], 0, 0, 0);
        }
    }

    // Epilogue: relu(acc + be1) dot We2, reduce over n.
    float esum[4][4];
    #pragma unroll
    for (int mt = 0; mt < 4; ++mt)
        #pragma unroll
        for (int r = 0; r < 4; ++r) esum[mt][r] = 0.f;

    #pragma unroll
    for (int nt = 0; nt < 4; ++nt) {
        int n = w * 64 + nt * 16 + m16;
        float b1 = be1[n], w2 = We2[n];
        #pragma unroll
        for (int mt = 0; mt < 4; ++mt)
            #pragma unroll
            for (int r = 0; r < 4; ++r) {
                float h = fmaxf(acc[mt][nt][r] + b1, 0.f);
                esum[mt][r] += h * w2;
            }
    }
    #pragma unroll
    for (int off = 1; off <= 8; off <<= 1)
        #pragma unroll
        for (int mt = 0; mt < 4; ++mt)
            #pragma unroll
            for (int r = 0; r < 4; ++r)
                esum[mt][r] += __shfl_xor(esum[mt][r], off, 64);
    if (m16 == 0) {
        #pragma unroll
        for (int mt = 0; mt < 4; ++mt)
            #pragma unroll
            for (int r = 0; r < 4; ++r)
                s_red[w][mt * 16 + quad * 4 + r] = esum[mt][r];
    }
    __syncthreads();
    if (tid < 64)
        edge_out[e0 + tid] = s_red[0][tid] + s_red[1][tid] + s_red[2][tid]
                           + s_red[3][tid] + be2[0];
}

// ---------- scatter-mean: XCD-sharded atomics ----------
// shard = blockIdx%8 rides the round-robin block->XCD dispatch: each XCD's L2
// holds its 3.3 MB seg slice, atomics become L2-local (perf heuristic only).
__global__ __launch_bounds__(256) void scatter_kernel(
    const float* __restrict__ z, const int* __restrict__ ei,
    const float* __restrict__ eattr, float* __restrict__ seg)
{
    const int shard = blockIdx.x & 7;
    const int chunk = blockIdx.x >> 3;
    const int lo = shard * NODES_PER_SHARD, hi = lo + NODES_PER_SHARD;
    const int wv = threadIdx.x >> 6, lane = threadIdx.x & 63;
    const int cs = chunk * SCAT_CHUNK;

    for (int i = 0; i < SCAT_CHUNK / 256; ++i) {
        int e  = cs + i * 256 + wv * 64 + lane;
        int d  = ei[N_EDGES + e];
        int s  = ei[e];
        float at = eattr[e];
        unsigned long long m = __ballot(d >= lo && d < hi);
        while (m) {
            int b = __ffsll((unsigned long long)m) - 1;
            m &= m - 1;
            int   dd = __shfl(d, b, 64);
            int   ss = __shfl(s, b, 64);
            float aa = __shfl(at, b, 64);
            float* segd = seg + (size_t)dd * SEG_STRIDE;
            float2 v = *(const float2*)&z[(size_t)ss * C_IN + lane * 2];
            atomicAdd(segd + 1 + lane * 2, v.x);
            atomicAdd(segd + 2 + lane * 2, v.y);
            if (lane == 0) {
                atomicAdd(segd, aa);
                atomicAdd(segd + 129, 1.0f);
            }
        }
    }
}

// ---------- normalize + node MLP (fp32, unchanged) ----------

__global__ void normalize_kernel(float* __restrict__ seg) {
    const long long t = (long long)blockIdx.x * 256 + threadIdx.x;
    if (t >= (long long)N_NODES * 129) return;
    const int n = (int)(t / 129);
    const int k = (int)(t % 129);
    const float cnt = seg[n * SEG_STRIDE + 129];
    const float v   = seg[n * SEG_STRIDE + k];
    seg[n * SEG_STRIDE + k] = (cnt > 0.0f) ? v / cnt : 0.0f;
}

__global__ __launch_bounds__(256) void node_kernel(
    const float* __restrict__ seg, const float* __restrict__ Wa1p,
    const float* __restrict__ ba1, const float* __restrict__ Wa2,
    const float* __restrict__ ba2, float* __restrict__ x_out)
{
    __shared__ float s_in[16][132];
    __shared__ float s_h[16][256];
    const int tid = threadIdx.x;
    const long long n0 = (long long)blockIdx.x * 16;

    for (int nn = 0; nn < 16; ++nn) {
        if (tid < 132) s_in[nn][tid] = seg[(n0 + nn) * SEG_STRIDE + tid];
    }
    __syncthreads();

    const int c = tid;
    float acc[16];
    #pragma unroll
    for (int nn = 0; nn < 16; ++nn) acc[nn] = 0.0f;

    for (int k4 = 0; k4 < 33; ++k4) {
        const float w0 = Wa1p[(k4 * 4 + 0) * C_HID + c];
        const float w1 = Wa1p[(k4 * 4 + 1) * C_HID + c];
        const float w2 = Wa1p[(k4 * 4 + 2) * C_HID + c];
        const float w3 = Wa1p[(k4 * 4 + 3) * C_HID + c];
        #pragma unroll
        for (int nn = 0; nn < 16; ++nn) {
            const float4 x = *(const float4*)&s_in[nn][k4 * 4];
            acc[nn] += x.x * w0 + x.y * w1 + x.z * w2 + x.w * w3;
        }
    }
    const float b1 = ba1[c];
    #pragma unroll
    for (int nn = 0; nn < 16; ++nn) s_h[nn][c] = fmaxf(acc[nn] + b1, 0.0f);
    __syncthreads();

    const int j = tid & 127;
    const int g = tid >> 7;
    float acc2[8];
    #pragma unroll
    for (int nn = 0; nn < 8; ++nn) acc2[nn] = 0.0f;

    for (int k4 = 0; k4 < 64; ++k4) {
        const float w0 = Wa2[(k4 * 4 + 0) * C_OUT + j];
        const float w1 = Wa2[(k4 * 4 + 1) * C_OUT + j];
        const float w2 = Wa2[(k4 * 4 + 2) * C_OUT + j];
        const float w3 = Wa2[(k4 * 4 + 3) * C_OUT + j];
        #pragma unroll
        for (int nn = 0; nn < 8; ++nn) {
            const float4 x = *(const float4*)&s_h[g * 8 + nn][k4 * 4];
            acc2[nn] += x.x * w0 + x.y * w1 + x.z * w2 + x.w * w3;
        }
    }
    const float b2 = ba2[j];
    #pragma unroll
    for (int nn = 0; nn < 8; ++nn)
        x_out[(n0 + g * 8 + nn) * C_OUT + j] = acc2[nn] + b2;
}

// ---------- launch ----------
// ws: [seg 26.4MB][Wa1p 135KB][zb 12.8MB][Bpack 128KB] ~= 39.5 MB

extern "C" void kernel_launch(void* const* d_in, const int* in_sizes, int n_in,
                              void* d_out, int out_size, void* d_ws, size_t ws_size,
                              hipStream_t stream) {
    const float* z     = (const float*)d_in[0];
    const int*   ei    = (const int*)d_in[1];     // int32 per harness contract
    const float* eattr = (const float*)d_in[2];
    const float* Wa1   = (const float*)d_in[3];
    const float* ba1   = (const float*)d_in[4];
    const float* Wa2   = (const float*)d_in[5];
    const float* ba2   = (const float*)d_in[6];
    const float* We1   = (const float*)d_in[7];
    const float* be1   = (const float*)d_in[8];
    const float* We2   = (const float*)d_in[9];
    const float* be2   = (const float*)d_in[10];

    float* x_out    = (float*)d_out;
    float* edge_out = x_out + (size_t)N_NODES * C_OUT;

    char* wsb = (char*)d_ws;
    float*          seg   = (float*)wsb;                                   // 26,400,000 B
    float*          Wa1p  = (float*)(wsb + 26400000);                      //    135,168 B
    unsigned short* zb    = (unsigned short*)(wsb + 26400000 + 135168);    // 12,800,000 B
    unsigned short* Bpack = (unsigned short*)(wsb + 26400000 + 135168 + 12800000); // 131,072 B

    hipMemsetAsync(seg, 0, (size_t)N_NODES * SEG_STRIDE * sizeof(float), stream);
    cast_z<<<(N_NODES * C_IN / 4 + 255) / 256, 256, 0, stream>>>(z, zb);
    prep_bpack<<<32, 256, 0, stream>>>(We1, Bpack);
    prep_wa1<<<132, 256, 0, stream>>>(Wa1, Wa1p);

    edge_mfma_kernel<<<N_EDGES / 64, 256, 0, stream>>>(zb, ei, Bpack, be1, We2, be2,
                                                       edge_out);
    scatter_kernel<<<SHARDS * (N_EDGES / SCAT_CHUNK), 256, 0, stream>>>(z, ei, eattr, seg);
    normalize_kernel<<<((long long)N_NODES * 129 + 255) / 256, 256, 0, stream>>>(seg);
    node_kernel<<<N_NODES / 16, 256, 0, stream>>>(seg, Wa1p, ba1, Wa2, ba2, x_out);
}

// Round 4
// 673.796 us; speedup vs baseline: 3.9463x; 1.8453x over previous
//
#include <hip/hip_runtime.h>

#define N_NODES 50000
#define N_EDGES 800000
#define C_IN    128
#define C_HID   256
#define C_OUT   128
#define SEG_STRIDE 132   // col 0: attr mean, 1..128: z_src mean, 129: count, 130-131: pad

typedef __bf16 bf16x8 __attribute__((ext_vector_type(8)));
typedef float  f32x4  __attribute__((ext_vector_type(4)));

__device__ __forceinline__ unsigned short f2bf(float x) {
    unsigned u = __float_as_uint(x);
    u = (u + 0x7FFF + ((u >> 16) & 1)) >> 16;   // RNE
    return (unsigned short)u;
}

// ---------- prep kernels ----------

__global__ void cast_z(const float* __restrict__ z, unsigned short* __restrict__ zb) {
    int t = blockIdx.x * 256 + threadIdx.x;          // one float4 per thread
    if (t >= N_NODES * C_IN / 4) return;
    float4 v = ((const float4*)z)[t];
    ushort4 o;
    o.x = f2bf(v.x); o.y = f2bf(v.y); o.z = f2bf(v.z); o.w = f2bf(v.w);
    ((ushort4*)zb)[t] = o;
}

// Pack We1 [256 k][256 n] fp32 -> bf16 MFMA B-fragment order.
__global__ void prep_bpack(const float* __restrict__ We1, unsigned short* __restrict__ Bpack) {
    int t = blockIdx.x * 256 + threadIdx.x;          // 8192 lane-slots
    if (t >= 8 * 16 * 64) return;
    int lane = t & 63, nt = (t >> 6) & 15, ks = t >> 10;
    int n  = nt * 16 + (lane & 15);
    int kb = ks * 32 + (lane >> 4) * 8;
    #pragma unroll
    for (int j = 0; j < 8; ++j)
        Bpack[t * 8 + j] = f2bf(We1[(kb + j) * C_HID + n]);
}

__global__ void prep_wa1(const float* __restrict__ Wa1, float* __restrict__ Wa1p) {
    int t = blockIdx.x * 256 + threadIdx.x;
    if (t >= 132 * 256) return;
    int k = t >> 8, c = t & 255;
    Wa1p[t] = (k < (C_IN + 1)) ? Wa1[k * C_HID + c] : 0.0f;
}

// ---------- CSR build: hist -> scan -> fill ----------

__global__ void hist_kernel(const int* __restrict__ ei, int* __restrict__ cnt) {
    int e = blockIdx.x * 256 + threadIdx.x;
    if (e < N_EDGES) atomicAdd(&cnt[ei[N_EDGES + e]], 1);
}

// One block, 256 threads; thread t scans bins [t*196, t*196+196).
__global__ __launch_bounds__(256) void scan_kernel(const int* __restrict__ cnt,
                                                   int* __restrict__ offsets) {
    const int tid = threadIdx.x;
    const int per = 196;                       // 256*196 = 50176 >= 50000
    const int base = tid * per;
    int sum = 0;
    for (int i = 0; i < per; ++i) {
        int b = base + i;
        if (b < N_NODES) sum += cnt[b];
    }
    const int lane = tid & 63, w = tid >> 6;
    int v = sum;
    #pragma unroll
    for (int off = 1; off < 64; off <<= 1) {
        int t = __shfl_up(v, off, 64);
        if (lane >= off) v += t;
    }
    __shared__ int s_w[4];
    if (lane == 63) s_w[w] = v;
    __syncthreads();
    int wbase = 0;
    for (int i = 0; i < w; ++i) wbase += s_w[i];
    int run = wbase + v - sum;                 // exclusive prefix for this thread
    for (int i = 0; i < per; ++i) {
        int b = base + i;
        if (b < N_NODES) { offsets[b] = run; run += cnt[b]; }
    }
    if (tid == 255) offsets[N_NODES] = run;    // total = N_EDGES
}

__global__ void fill_kernel(const int* __restrict__ ei, const float* __restrict__ eattr,
                            const int* __restrict__ offsets, int* __restrict__ cursor,
                            int* __restrict__ esrc, float* __restrict__ eatt) {
    int e = blockIdx.x * 256 + threadIdx.x;
    if (e >= N_EDGES) return;
    int d = ei[N_EDGES + e];
    int pos = atomicAdd(&cursor[d], 1);
    int slot = offsets[d] + pos;
    esrc[slot] = ei[e];
    eatt[slot] = eattr[e];
}

// ---------- gather-mean: one wave per node, no feature atomics ----------
// Fuses normalization: writes struct_ctx directly.
__global__ __launch_bounds__(256) void gather_kernel(
    const float* __restrict__ z, const int* __restrict__ offsets,
    const int* __restrict__ esrc, const float* __restrict__ eatt,
    float* __restrict__ seg)
{
    const int w = threadIdx.x >> 6, lane = threadIdx.x & 63;
    const int n = blockIdx.x * 4 + w;
    if (n >= N_NODES) return;
    const int beg = offsets[n], end = offsets[n + 1], deg = end - beg;

    float2 acc = {0.f, 0.f};                   // lane owns channels lane*2, lane*2+1
    for (int i = beg; i < end; ++i) {
        int s = esrc[i];
        float2 v = *(const float2*)&z[(size_t)s * C_IN + lane * 2];
        acc.x += v.x; acc.y += v.y;
    }
    float asum = 0.f;
    for (int i = beg + lane; i < end; i += 64) asum += eatt[i];
    #pragma unroll
    for (int off = 1; off < 64; off <<= 1) asum += __shfl_xor(asum, off, 64);

    const float inv = (deg > 0) ? 1.0f / (float)deg : 0.0f;
    float* segn = seg + (size_t)n * SEG_STRIDE;
    segn[1 + lane * 2] = acc.x * inv;
    segn[2 + lane * 2] = acc.y * inv;
    if (lane == 0) { segn[0] = asum * inv; segn[129] = (float)deg; }
}

// ---------- edge MLP: bf16 MFMA, fused layer2 dot (unchanged) ----------
__global__ __launch_bounds__(256, 2) void edge_mfma_kernel(
    const unsigned short* __restrict__ zb, const int* __restrict__ ei,
    const unsigned short* __restrict__ Bpack,
    const float* __restrict__ be1, const float* __restrict__ We2,
    const float* __restrict__ be2, float* __restrict__ edge_out)
{
    __shared__ __align__(16) unsigned short s_a[64][264];
    __shared__ float s_red[4][64];
    const int tid  = threadIdx.x;
    const int lane = tid & 63, w = tid >> 6;
    const long long e0 = (long long)blockIdx.x * 64;

    bf16x8 bfr[8][4];
    {
        const bf16x8* bp = (const bf16x8*)Bpack;
        #pragma unroll
        for (int ks = 0; ks < 8; ++ks)
            #pragma unroll
            for (int nt = 0; nt < 4; ++nt)
                bfr[ks][nt] = bp[(ks * 16 + (w * 4 + nt)) * 64 + lane];
    }

    {
        const int l16 = tid & 15;
        #pragma unroll
        for (int it = 0; it < 8; ++it) {
            int hr   = it * 16 + (tid >> 4);
            int e    = (int)(e0 + (hr >> 1));
            int half = hr & 1;
            int node = half ? ei[N_EDGES + e] : ei[e];
            bf16x8 v = *(const bf16x8*)(zb + (size_t)node * C_IN + l16 * 8);
            *(bf16x8*)&s_a[hr >> 1][half * 128 + l16 * 8] = v;
        }
    }
    __syncthreads();

    f32x4 acc[4][4];
    #pragma unroll
    for (int mt = 0; mt < 4; ++mt)
        #pragma unroll
        for (int nt = 0; nt < 4; ++nt)
            acc[mt][nt] = (f32x4){0.f, 0.f, 0.f, 0.f};

    const int m16 = lane & 15, quad = lane >> 4;
    #pragma unroll
    for (int ks = 0; ks < 8; ++ks) {
        #pragma unroll
        for (int mt = 0; mt < 4; ++mt) {
            bf16x8 a = *(const bf16x8*)&s_a[mt * 16 + m16][ks * 32 + quad * 8];
            #pragma unroll
            for (int nt = 0; nt < 4; ++nt)
                acc[mt][nt] = __builtin_amdgcn_mfma_f32_16x16x32_bf16(
                    a, bfr[ks][nt], acc[mt][nt], 0, 0, 0);
        }
    }

    float esum[4][4];
    #pragma unroll
    for (int mt = 0; mt < 4; ++mt)
        #pragma unroll
        for (int r = 0; r < 4; ++r) esum[mt][r] = 0.f;

    #pragma unroll
    for (int nt = 0; nt < 4; ++nt) {
        int n = w * 64 + nt * 16 + m16;
        float b1 = be1[n], w2 = We2[n];
        #pragma unroll
        for (int mt = 0; mt < 4; ++mt)
            #pragma unroll
            for (int r = 0; r < 4; ++r) {
                float h = fmaxf(acc[mt][nt][r] + b1, 0.f);
                esum[mt][r] += h * w2;
            }
    }
    #pragma unroll
    for (int off = 1; off <= 8; off <<= 1)
        #pragma unroll
        for (int mt = 0; mt < 4; ++mt)
            #pragma unroll
            for (int r = 0; r < 4; ++r)
                esum[mt][r] += __shfl_xor(esum[mt][r], off, 64);
    if (m16 == 0) {
        #pragma unroll
        for (int mt = 0; mt < 4; ++mt)
            #pragma unroll
            for (int r = 0; r < 4; ++r)
                s_red[w][mt * 16 + quad * 4 + r] = esum[mt][r];
    }
    __syncthreads();
    if (tid < 64)
        edge_out[e0 + tid] = s_red[0][tid] + s_red[1][tid] + s_red[2][tid]
                           + s_red[3][tid] + be2[0];
}

// ---------- node MLP (fp32, unchanged) ----------
__global__ __launch_bounds__(256) void node_kernel(
    const float* __restrict__ seg, const float* __restrict__ Wa1p,
    const float* __restrict__ ba1, const float* __restrict__ Wa2,
    const float* __restrict__ ba2, float* __restrict__ x_out)
{
    __shared__ float s_in[16][132];
    __shared__ float s_h[16][256];
    const int tid = threadIdx.x;
    const long long n0 = (long long)blockIdx.x * 16;

    for (int nn = 0; nn < 16; ++nn) {
        if (tid < 132) s_in[nn][tid] = seg[(n0 + nn) * SEG_STRIDE + tid];
    }
    __syncthreads();

    const int c = tid;
    float acc[16];
    #pragma unroll
    for (int nn = 0; nn < 16; ++nn) acc[nn] = 0.0f;

    for (int k4 = 0; k4 < 33; ++k4) {
        const float w0 = Wa1p[(k4 * 4 + 0) * C_HID + c];
        const float w1 = Wa1p[(k4 * 4 + 1) * C_HID + c];
        const float w2 = Wa1p[(k4 * 4 + 2) * C_HID + c];
        const float w3 = Wa1p[(k4 * 4 + 3) * C_HID + c];
        #pragma unroll
        for (int nn = 0; nn < 16; ++nn) {
            const float4 x = *(const float4*)&s_in[nn][k4 * 4];
            acc[nn] += x.x * w0 + x.y * w1 + x.z * w2 + x.w * w3;
        }
    }
    const float b1 = ba1[c];
    #pragma unroll
    for (int nn = 0; nn < 16; ++nn) s_h[nn][c] = fmaxf(acc[nn] + b1, 0.0f);
    __syncthreads();

    const int j = tid & 127;
    const int g = tid >> 7;
    float acc2[8];
    #pragma unroll
    for (int nn = 0; nn < 8; ++nn) acc2[nn] = 0.0f;

    for (int k4 = 0; k4 < 64; ++k4) {
        const float w0 = Wa2[(k4 * 4 + 0) * C_OUT + j];
        const float w1 = Wa2[(k4 * 4 + 1) * C_OUT + j];
        const float w2 = Wa2[(k4 * 4 + 2) * C_OUT + j];
        const float w3 = Wa2[(k4 * 4 + 3) * C_OUT + j];
        #pragma unroll
        for (int nn = 0; nn < 8; ++nn) {
            const float4 x = *(const float4*)&s_h[g * 8 + nn][k4 * 4];
            acc2[nn] += x.x * w0 + x.y * w1 + x.z * w2 + x.w * w3;
        }
    }
    const float b2 = ba2[j];
    #pragma unroll
    for (int nn = 0; nn < 8; ++nn)
        x_out[(n0 + g * 8 + nn) * C_OUT + j] = acc2[nn] + b2;
}

// ---------- launch ----------
// ws layout (bytes):
//   seg     26,400,000
//   Wa1p       135,168
//   zb      12,800,000
//   Bpack      131,072
//   cnt        200,064
//   cursor     200,064   (cnt+cursor memset together)
//   offsets    200,064
//   esrc     3,200,000
//   eatt     3,200,000   => ~46.5 MB

extern "C" void kernel_launch(void* const* d_in, const int* in_sizes, int n_in,
                              void* d_out, int out_size, void* d_ws, size_t ws_size,
                              hipStream_t stream) {
    const float* z     = (const float*)d_in[0];
    const int*   ei    = (const int*)d_in[1];     // int32 per harness contract
    const float* eattr = (const float*)d_in[2];
    const float* Wa1   = (const float*)d_in[3];
    const float* ba1   = (const float*)d_in[4];
    const float* Wa2   = (const float*)d_in[5];
    const float* ba2   = (const float*)d_in[6];
    const float* We1   = (const float*)d_in[7];
    const float* be1   = (const float*)d_in[8];
    const float* We2   = (const float*)d_in[9];
    const float* be2   = (const float*)d_in[10];

    float* x_out    = (float*)d_out;
    float* edge_out = x_out + (size_t)N_NODES * C_OUT;

    char* wsb = (char*)d_ws;
    size_t off = 0;
    float*          seg     = (float*)(wsb + off);          off += 26400000;
    float*          Wa1p    = (float*)(wsb + off);          off += 135168;
    unsigned short* zb      = (unsigned short*)(wsb + off); off += 12800000;
    unsigned short* Bpack   = (unsigned short*)(wsb + off); off += 131072;
    int*            cnt     = (int*)(wsb + off);            off += 200064;
    int*            cursor  = (int*)(wsb + off);            off += 200064;
    int*            offsets = (int*)(wsb + off);            off += 200064;
    int*            esrc    = (int*)(wsb + off);            off += 3200000;
    float*          eatt    = (float*)(wsb + off);          off += 3200000;

    hipMemsetAsync(cnt, 0, 2 * 200064, stream);   // cnt + cursor (adjacent)

    cast_z<<<(N_NODES * C_IN / 4 + 255) / 256, 256, 0, stream>>>(z, zb);
    prep_bpack<<<32, 256, 0, stream>>>(We1, Bpack);
    prep_wa1<<<132, 256, 0, stream>>>(Wa1, Wa1p);

    hist_kernel<<<(N_EDGES + 255) / 256, 256, 0, stream>>>(ei, cnt);
    scan_kernel<<<1, 256, 0, stream>>>(cnt, offsets);
    fill_kernel<<<(N_EDGES + 255) / 256, 256, 0, stream>>>(ei, eattr, offsets, cursor,
                                                           esrc, eatt);

    edge_mfma_kernel<<<N_EDGES / 64, 256, 0, stream>>>(zb, ei, Bpack, be1, We2, be2,
                                                       edge_out);

    gather_kernel<<<(N_NODES + 3) / 4, 256, 0, stream>>>(z, offsets, esrc, eatt, seg);
    node_kernel<<<N_NODES / 16, 256, 0, stream>>>(seg, Wa1p, ba1, Wa2, ba2, x_out);
}

// Round 5
// 541.168 us; speedup vs baseline: 4.9134x; 1.2451x over previous
//
#include <hip/hip_runtime.h>

#define N_NODES 50000
#define N_EDGES 800000
#define C_IN    128
#define C_HID   256
#define C_OUT   128
#define SEGB_STRIDE 160   // bf16: [z mean 0..127 | attr 128 | zeros 129..159]

typedef __bf16 bf16x8 __attribute__((ext_vector_type(8)));
typedef float  f32x4  __attribute__((ext_vector_type(4)));

__device__ __forceinline__ unsigned short f2bf(float x) {
    unsigned u = __float_as_uint(x);
    u = (u + 0x7FFF + ((u >> 16) & 1)) >> 16;   // RNE
    return (unsigned short)u;
}

// ---------- prep kernels ----------

__global__ void cast_z(const float* __restrict__ z, unsigned short* __restrict__ zb) {
    int t = blockIdx.x * 256 + threadIdx.x;
    if (t >= N_NODES * C_IN / 4) return;
    float4 v = ((const float4*)z)[t];
    ushort4 o;
    o.x = f2bf(v.x); o.y = f2bf(v.y); o.z = f2bf(v.z); o.w = f2bf(v.w);
    ((ushort4*)zb)[t] = o;
}

// We1 [256k][256n] -> bf16 B-frag order (edge layer1), 8 ks x 16 nt
__global__ void prep_bpack(const float* __restrict__ We1, unsigned short* __restrict__ Bpack) {
    int t = blockIdx.x * 256 + threadIdx.x;
    if (t >= 8 * 16 * 64) return;
    int lane = t & 63, nt = (t >> 6) & 15, ks = t >> 10;
    int n  = nt * 16 + (lane & 15);
    int kb = ks * 32 + (lane >> 4) * 8;
    #pragma unroll
    for (int j = 0; j < 8; ++j)
        Bpack[t * 8 + j] = f2bf(We1[(kb + j) * C_HID + n]);
}

// Wa1 [129k][256n] -> bf16 B-frags for node layer1 with segb column order:
// segb k: 0..127 = z chan k  (Wa1 row k+1), 128 = attr (Wa1 row 0), >=129 = 0.
__global__ void prep_wa1b(const float* __restrict__ Wa1, unsigned short* __restrict__ Wa1b) {
    int t = blockIdx.x * 256 + threadIdx.x;
    if (t >= 5 * 16 * 64) return;
    int lane = t & 63, nt = (t >> 6) & 15, ks = t >> 10;      // ks 0..4
    int n = nt * 16 + (lane & 15);
    #pragma unroll
    for (int j = 0; j < 8; ++j) {
        int k = ks * 32 + (lane >> 4) * 8 + j;
        float v = 0.f;
        if (k < 128)       v = Wa1[(k + 1) * C_HID + n];
        else if (k == 128) v = Wa1[0 * C_HID + n];
        Wa1b[t * 8 + j] = f2bf(v);
    }
}

// Wa2 [256k][128n] -> bf16 B-frags (node layer2), 8 ks x 8 nt
__global__ void prep_wa2b(const float* __restrict__ Wa2, unsigned short* __restrict__ Wa2b) {
    int t = blockIdx.x * 256 + threadIdx.x;
    if (t >= 8 * 8 * 64) return;
    int lane = t & 63, nt = (t >> 6) & 7, ks = t >> 9;        // ks 0..7
    int n  = nt * 16 + (lane & 15);
    int kb = ks * 32 + (lane >> 4) * 8;
    #pragma unroll
    for (int j = 0; j < 8; ++j)
        Wa2b[t * 8 + j] = f2bf(Wa2[(kb + j) * C_OUT + n]);
}

// ---------- CSR build ----------

__global__ void hist_kernel(const int* __restrict__ ei, int* __restrict__ cnt) {
    int e = blockIdx.x * 256 + threadIdx.x;
    if (e < N_EDGES) atomicAdd(&cnt[ei[N_EDGES + e]], 1);
}

__global__ __launch_bounds__(256) void scan_kernel(const int* __restrict__ cnt,
                                                   int* __restrict__ offsets) {
    const int tid = threadIdx.x;
    const int per = 196;
    const int base = tid * per;
    int sum = 0;
    for (int i = 0; i < per; ++i) {
        int b = base + i;
        if (b < N_NODES) sum += cnt[b];
    }
    const int lane = tid & 63, w = tid >> 6;
    int v = sum;
    #pragma unroll
    for (int off = 1; off < 64; off <<= 1) {
        int t = __shfl_up(v, off, 64);
        if (lane >= off) v += t;
    }
    __shared__ int s_w[4];
    if (lane == 63) s_w[w] = v;
    __syncthreads();
    int wbase = 0;
    for (int i = 0; i < w; ++i) wbase += s_w[i];
    int run = wbase + v - sum;
    for (int i = 0; i < per; ++i) {
        int b = base + i;
        if (b < N_NODES) { offsets[b] = run; run += cnt[b]; }
    }
    if (tid == 255) offsets[N_NODES] = run;
}

__global__ void fill_kernel(const int* __restrict__ ei, const float* __restrict__ eattr,
                            const int* __restrict__ offsets, int* __restrict__ cursor,
                            int* __restrict__ esrc, float* __restrict__ eatt) {
    int e = blockIdx.x * 256 + threadIdx.x;
    if (e >= N_EDGES) return;
    int d = ei[N_EDGES + e];
    int pos = atomicAdd(&cursor[d], 1);
    int slot = offsets[d] + pos;
    esrc[slot] = ei[e];
    eatt[slot] = eattr[e];
}

// ---------- gather-mean (bf16 in, bf16 out, fused normalize) ----------
__global__ __launch_bounds__(256) void gather_kernel(
    const unsigned short* __restrict__ zb, const int* __restrict__ offsets,
    const int* __restrict__ esrc, const float* __restrict__ eatt,
    unsigned short* __restrict__ segb)
{
    const int w = threadIdx.x >> 6, lane = threadIdx.x & 63;
    const int n = blockIdx.x * 4 + w;
    if (n >= N_NODES) return;
    const int beg = offsets[n], end = offsets[n + 1], deg = end - beg;

    float ax = 0.f, ay = 0.f;                  // lane owns channels lane*2, lane*2+1
    for (int i = beg; i < end; ++i) {
        int s = esrc[i];
        unsigned u = *(const unsigned*)(zb + (size_t)s * C_IN + lane * 2);
        ax += __uint_as_float(u << 16);
        ay += __uint_as_float(u & 0xffff0000u);
    }
    float asum = 0.f;
    for (int i = beg + lane; i < end; i += 64) asum += eatt[i];
    #pragma unroll
    for (int off = 1; off < 64; off <<= 1) asum += __shfl_xor(asum, off, 64);

    const float inv = (deg > 0) ? 1.0f / (float)deg : 0.0f;
    unsigned short* segn = segb + (size_t)n * SEGB_STRIDE;
    ushort2 o; o.x = f2bf(ax * inv); o.y = f2bf(ay * inv);
    *(ushort2*)(segn + lane * 2) = o;
    if (lane < 16) {
        ushort2 p; p.x = (lane == 0) ? f2bf(asum * inv) : 0; p.y = 0;
        *(ushort2*)(segn + 128 + lane * 2) = p;   // attr @128, zeros 129..159
    }
}

// ---------- edge MLP: bf16 MFMA, fused layer2 dot ----------
__global__ __launch_bounds__(256, 2) void edge_mfma_kernel(
    const unsigned short* __restrict__ zb, const int* __restrict__ ei,
    const unsigned short* __restrict__ Bpack,
    const float* __restrict__ be1, const float* __restrict__ We2,
    const float* __restrict__ be2, float* __restrict__ edge_out)
{
    __shared__ __align__(16) unsigned short s_a[64][264];
    __shared__ float s_red[4][64];
    const int tid  = threadIdx.x;
    const int lane = tid & 63, w = tid >> 6;
    const long long e0 = (long long)blockIdx.x * 64;

    bf16x8 bfr[8][4];
    {
        const bf16x8* bp = (const bf16x8*)Bpack;
        #pragma unroll
        for (int ks = 0; ks < 8; ++ks)
            #pragma unroll
            for (int nt = 0; nt < 4; ++nt)
                bfr[ks][nt] = bp[(ks * 16 + (w * 4 + nt)) * 64 + lane];
    }

    {
        const int l16 = tid & 15;
        #pragma unroll
        for (int it = 0; it < 8; ++it) {
            int hr   = it * 16 + (tid >> 4);
            int e    = (int)(e0 + (hr >> 1));
            int half = hr & 1;
            int node = half ? ei[N_EDGES + e] : ei[e];
            bf16x8 v = *(const bf16x8*)(zb + (size_t)node * C_IN + l16 * 8);
            *(bf16x8*)&s_a[hr >> 1][half * 128 + l16 * 8] = v;
        }
    }
    __syncthreads();

    f32x4 acc[4][4];
    #pragma unroll
    for (int mt = 0; mt < 4; ++mt)
        #pragma unroll
        for (int nt = 0; nt < 4; ++nt)
            acc[mt][nt] = (f32x4){0.f, 0.f, 0.f, 0.f};

    const int m16 = lane & 15, quad = lane >> 4;
    #pragma unroll
    for (int ks = 0; ks < 8; ++ks) {
        #pragma unroll
        for (int mt = 0; mt < 4; ++mt) {
            bf16x8 a = *(const bf16x8*)&s_a[mt * 16 + m16][ks * 32 + quad * 8];
            #pragma unroll
            for (int nt = 0; nt < 4; ++nt)
                acc[mt][nt] = __builtin_amdgcn_mfma_f32_16x16x32_bf16(
                    a, bfr[ks][nt], acc[mt][nt], 0, 0, 0);
        }
    }

    float esum[4][4];
    #pragma unroll
    for (int mt = 0; mt < 4; ++mt)
        #pragma unroll
        for (int r = 0; r < 4; ++r) esum[mt][r] = 0.f;

    #pragma unroll
    for (int nt = 0; nt < 4; ++nt) {
        int n = w * 64 + nt * 16 + m16;
        float b1 = be1[n], w2 = We2[n];
        #pragma unroll
        for (int mt = 0; mt < 4; ++mt)
            #pragma unroll
            for (int r = 0; r < 4; ++r) {
                float h = fmaxf(acc[mt][nt][r] + b1, 0.f);
                esum[mt][r] += h * w2;
            }
    }
    #pragma unroll
    for (int off = 1; off <= 8; off <<= 1)
        #pragma unroll
        for (int mt = 0; mt < 4; ++mt)
            #pragma unroll
            for (int r = 0; r < 4; ++r)
                esum[mt][r] += __shfl_xor(esum[mt][r], off, 64);
    if (m16 == 0) {
        #pragma unroll
        for (int mt = 0; mt < 4; ++mt)
            #pragma unroll
            for (int r = 0; r < 4; ++r)
                s_red[w][mt * 16 + quad * 4 + r] = esum[mt][r];
    }
    __syncthreads();
    if (tid < 64)
        edge_out[e0 + tid] = s_red[0][tid] + s_red[1][tid] + s_red[2][tid]
                           + s_red[3][tid] + be2[0];
}

// ---------- node MLP: bf16 MFMA, both layers, h via LDS round-trip ----------
// Block = 64 nodes. L1: M64 x K160 x N256 (wave w owns n [w*64,w*64+64)).
// L2: M64 x K256 x N128 (wave w owns n [w*32,w*32+32)).
__global__ __launch_bounds__(256, 2) void node_mfma_kernel(
    const unsigned short* __restrict__ segb, const unsigned short* __restrict__ Wa1b,
    const float* __restrict__ ba1, const unsigned short* __restrict__ Wa2b,
    const float* __restrict__ ba2, float* __restrict__ x_out)
{
    __shared__ __align__(16) unsigned short s_a[64][168];  // pad: 336B stride, 2-way free
    __shared__ __align__(16) unsigned short s_h[64][264];  // pad: 528B stride, 2-way free
    const int tid  = threadIdx.x;
    const int lane = tid & 63, w = tid >> 6;
    const int m16 = lane & 15, quad = lane >> 4;
    const int n0 = blockIdx.x * 64;

    // Stage A: 64 rows x 320B, contiguous in segb. 1280 16B-chunks.
    {
        const unsigned short* src = segb + (size_t)n0 * SEGB_STRIDE;
        #pragma unroll
        for (int i = 0; i < 5; ++i) {
            int c = tid + i * 256;
            int row = c / 20, col = c - row * 20;
            *(uint4*)&s_a[row][col * 8] = *(const uint4*)(src + c * 8);
        }
    }

    // Layer-1 B frags
    bf16x8 bfr1[5][4];
    {
        const bf16x8* bp = (const bf16x8*)Wa1b;
        #pragma unroll
        for (int ks = 0; ks < 5; ++ks)
            #pragma unroll
            for (int nt = 0; nt < 4; ++nt)
                bfr1[ks][nt] = bp[(ks * 16 + (w * 4 + nt)) * 64 + lane];
    }
    __syncthreads();

    f32x4 acc1[4][4];
    #pragma unroll
    for (int mt = 0; mt < 4; ++mt)
        #pragma unroll
        for (int nt = 0; nt < 4; ++nt)
            acc1[mt][nt] = (f32x4){0.f, 0.f, 0.f, 0.f};

    #pragma unroll
    for (int ks = 0; ks < 5; ++ks) {
        #pragma unroll
        for (int mt = 0; mt < 4; ++mt) {
            bf16x8 a = *(const bf16x8*)&s_a[mt * 16 + m16][ks * 32 + quad * 8];
            #pragma unroll
            for (int nt = 0; nt < 4; ++nt)
                acc1[mt][nt] = __builtin_amdgcn_mfma_f32_16x16x32_bf16(
                    a, bfr1[ks][nt], acc1[mt][nt], 0, 0, 0);
        }
    }

    // relu + bias, write bf16 h to LDS (C-layout -> A-layout round trip)
    #pragma unroll
    for (int nt = 0; nt < 4; ++nt) {
        const int chan = w * 64 + nt * 16 + m16;
        const float b1 = ba1[chan];
        #pragma unroll
        for (int mt = 0; mt < 4; ++mt)
            #pragma unroll
            for (int r = 0; r < 4; ++r) {
                const int node = mt * 16 + quad * 4 + r;
                s_h[node][chan] = f2bf(fmaxf(acc1[mt][nt][r] + b1, 0.f));
            }
    }

    // Layer-2 B frags
    bf16x8 bfr2[8][2];
    {
        const bf16x8* bp = (const bf16x8*)Wa2b;
        #pragma unroll
        for (int ks = 0; ks < 8; ++ks)
            #pragma unroll
            for (int nt = 0; nt < 2; ++nt)
                bfr2[ks][nt] = bp[(ks * 8 + (w * 2 + nt)) * 64 + lane];
    }
    __syncthreads();

    f32x4 acc2[4][2];
    #pragma unroll
    for (int mt = 0; mt < 4; ++mt)
        #pragma unroll
        for (int nt = 0; nt < 2; ++nt)
            acc2[mt][nt] = (f32x4){0.f, 0.f, 0.f, 0.f};

    #pragma unroll
    for (int ks = 0; ks < 8; ++ks) {
        #pragma unroll
        for (int mt = 0; mt < 4; ++mt) {
            bf16x8 a = *(const bf16x8*)&s_h[mt * 16 + m16][ks * 32 + quad * 8];
            #pragma unroll
            for (int nt = 0; nt < 2; ++nt)
                acc2[mt][nt] = __builtin_amdgcn_mfma_f32_16x16x32_bf16(
                    a, bfr2[ks][nt], acc2[mt][nt], 0, 0, 0);
        }
    }

    #pragma unroll
    for (int nt = 0; nt < 2; ++nt) {
        const int j = w * 32 + nt * 16 + m16;
        const float b2 = ba2[j];
        #pragma unroll
        for (int mt = 0; mt < 4; ++mt)
            #pragma unroll
            for (int r = 0; r < 4; ++r) {
                const int node = n0 + mt * 16 + quad * 4 + r;
                if (node < N_NODES)
                    x_out[(size_t)node * C_OUT + j] = acc2[mt][nt][r] + b2;
            }
    }
}

// ---------- launch ----------
// ws layout (bytes):
//   segb    16,015,360   (50048 rows x 160 bf16; 48 pad rows for last M-tile)
//   zb      12,800,000
//   Bpack      131,072
//   Wa1b        81,920
//   Wa2b        65,536
//   cnt        200,064
//   cursor     200,064
//   offsets    200,064
//   esrc     3,200,000
//   eatt     3,200,000    => ~36.1 MB

extern "C" void kernel_launch(void* const* d_in, const int* in_sizes, int n_in,
                              void* d_out, int out_size, void* d_ws, size_t ws_size,
                              hipStream_t stream) {
    const float* z     = (const float*)d_in[0];
    const int*   ei    = (const int*)d_in[1];     // int32 per harness contract
    const float* eattr = (const float*)d_in[2];
    const float* Wa1   = (const float*)d_in[3];
    const float* ba1   = (const float*)d_in[4];
    const float* Wa2   = (const float*)d_in[5];
    const float* ba2   = (const float*)d_in[6];
    const float* We1   = (const float*)d_in[7];
    const float* be1   = (const float*)d_in[8];
    const float* We2   = (const float*)d_in[9];
    const float* be2   = (const float*)d_in[10];

    float* x_out    = (float*)d_out;
    float* edge_out = x_out + (size_t)N_NODES * C_OUT;

    char* wsb = (char*)d_ws;
    size_t off = 0;
    unsigned short* segb    = (unsigned short*)(wsb + off); off += 16015360;
    unsigned short* zb      = (unsigned short*)(wsb + off); off += 12800000;
    unsigned short* Bpack   = (unsigned short*)(wsb + off); off += 131072;
    unsigned short* Wa1b    = (unsigned short*)(wsb + off); off += 81920;
    unsigned short* Wa2b    = (unsigned short*)(wsb + off); off += 65536;
    int*            cnt     = (int*)(wsb + off);            off += 200064;
    int*            cursor  = (int*)(wsb + off);            off += 200064;
    int*            offsets = (int*)(wsb + off);            off += 200064;
    int*            esrc    = (int*)(wsb + off);            off += 3200000;
    float*          eatt    = (float*)(wsb + off);          off += 3200000;

    hipMemsetAsync(cnt, 0, 2 * 200064, stream);   // cnt + cursor (adjacent)

    cast_z<<<(N_NODES * C_IN / 4 + 255) / 256, 256, 0, stream>>>(z, zb);
    prep_bpack<<<32, 256, 0, stream>>>(We1, Bpack);
    prep_wa1b<<<20, 256, 0, stream>>>(Wa1, Wa1b);
    prep_wa2b<<<16, 256, 0, stream>>>(Wa2, Wa2b);

    hist_kernel<<<(N_EDGES + 255) / 256, 256, 0, stream>>>(ei, cnt);
    scan_kernel<<<1, 256, 0, stream>>>(cnt, offsets);
    fill_kernel<<<(N_EDGES + 255) / 256, 256, 0, stream>>>(ei, eattr, offsets, cursor,
                                                           esrc, eatt);

    edge_mfma_kernel<<<N_EDGES / 64, 256, 0, stream>>>(zb, ei, Bpack, be1, We2, be2,
                                                       edge_out);

    gather_kernel<<<(N_NODES + 3) / 4, 256, 0, stream>>>(zb, offsets, esrc, eatt, segb);
    node_mfma_kernel<<<(N_NODES + 63) / 64, 256, 0, stream>>>(segb, Wa1b, ba1, Wa2b,
                                                              ba2, x_out);
}

// Round 6
// 488.878 us; speedup vs baseline: 5.4390x; 1.1070x over previous
//
#include <hip/hip_runtime.h>

#define N_NODES 50000
#define N_EDGES 800000
#define C_IN    128
#define C_HID   256
#define C_OUT   128
#define SEGB_STRIDE 160   // bf16: [z mean 0..127 | attr 128 | zeros 129..159]

typedef __bf16 bf16x8 __attribute__((ext_vector_type(8)));
typedef float  f32x4  __attribute__((ext_vector_type(4)));

__device__ __forceinline__ unsigned short f2bf(float x) {
    unsigned u = __float_as_uint(x);
    u = (u + 0x7FFF + ((u >> 16) & 1)) >> 16;   // RNE
    return (unsigned short)u;
}

// ---------- prep kernels ----------

__global__ void cast_z(const float* __restrict__ z, unsigned short* __restrict__ zb) {
    int t = blockIdx.x * 256 + threadIdx.x;
    if (t >= N_NODES * C_IN / 4) return;
    float4 v = ((const float4*)z)[t];
    ushort4 o;
    o.x = f2bf(v.x); o.y = f2bf(v.y); o.z = f2bf(v.z); o.w = f2bf(v.w);
    ((ushort4*)zb)[t] = o;
}

// We1 [256k][256n] -> bf16 B-frag order (edge layer1), 8 ks x 16 nt
__global__ void prep_bpack(const float* __restrict__ We1, unsigned short* __restrict__ Bpack) {
    int t = blockIdx.x * 256 + threadIdx.x;
    if (t >= 8 * 16 * 64) return;
    int lane = t & 63, nt = (t >> 6) & 15, ks = t >> 10;
    int n  = nt * 16 + (lane & 15);
    int kb = ks * 32 + (lane >> 4) * 8;
    #pragma unroll
    for (int j = 0; j < 8; ++j)
        Bpack[t * 8 + j] = f2bf(We1[(kb + j) * C_HID + n]);
}

// Wa1 [129k][256n] -> bf16 B-frags for node layer1 with segb column order.
__global__ void prep_wa1b(const float* __restrict__ Wa1, unsigned short* __restrict__ Wa1b) {
    int t = blockIdx.x * 256 + threadIdx.x;
    if (t >= 5 * 16 * 64) return;
    int lane = t & 63, nt = (t >> 6) & 15, ks = t >> 10;      // ks 0..4
    int n = nt * 16 + (lane & 15);
    #pragma unroll
    for (int j = 0; j < 8; ++j) {
        int k = ks * 32 + (lane >> 4) * 8 + j;
        float v = 0.f;
        if (k < 128)       v = Wa1[(k + 1) * C_HID + n];
        else if (k == 128) v = Wa1[0 * C_HID + n];
        Wa1b[t * 8 + j] = f2bf(v);
    }
}

// Wa2 [256k][128n] -> bf16 B-frags (node layer2), 8 ks x 8 nt
__global__ void prep_wa2b(const float* __restrict__ Wa2, unsigned short* __restrict__ Wa2b) {
    int t = blockIdx.x * 256 + threadIdx.x;
    if (t >= 8 * 8 * 64) return;
    int lane = t & 63, nt = (t >> 6) & 7, ks = t >> 9;        // ks 0..7
    int n  = nt * 16 + (lane & 15);
    int kb = ks * 32 + (lane >> 4) * 8;
    #pragma unroll
    for (int j = 0; j < 8; ++j)
        Wa2b[t * 8 + j] = f2bf(Wa2[(kb + j) * C_OUT + n]);
}

// ---------- CSR build ----------

__global__ void hist_kernel(const int* __restrict__ ei, int* __restrict__ cnt) {
    int e = blockIdx.x * 256 + threadIdx.x;
    if (e < N_EDGES) atomicAdd(&cnt[ei[N_EDGES + e]], 1);
}

// cnt zero-padded to 50176 ints so int4 reads need no bounds checks.
__global__ __launch_bounds__(256) void scan_kernel(const int* __restrict__ cnt,
                                                   int* __restrict__ offsets) {
    const int tid = threadIdx.x;
    const int per = 196;                        // 49 int4
    const int base = tid * per;
    const int4* c4 = (const int4*)(cnt + base);
    int sum = 0;
    #pragma unroll 7
    for (int i = 0; i < 49; ++i) {
        int4 v = c4[i];
        sum += v.x + v.y + v.z + v.w;
    }
    const int lane = tid & 63, w = tid >> 6;
    int v = sum;
    #pragma unroll
    for (int off = 1; off < 64; off <<= 1) {
        int t = __shfl_up(v, off, 64);
        if (lane >= off) v += t;
    }
    __shared__ int s_w[4];
    if (lane == 63) s_w[w] = v;
    __syncthreads();
    int wbase = 0;
    for (int i = 0; i < w; ++i) wbase += s_w[i];
    int run = wbase + v - sum;
    for (int i = 0; i < per; ++i) {
        int b = base + i;
        if (b < N_NODES) { offsets[b] = run; run += cnt[b]; }
    }
    if (tid == 255) offsets[N_NODES] = run;
}

__global__ void fill_kernel(const int* __restrict__ ei, const float* __restrict__ eattr,
                            const int* __restrict__ offsets, int* __restrict__ cursor,
                            int* __restrict__ esrc, float* __restrict__ eatt) {
    int e = blockIdx.x * 256 + threadIdx.x;
    if (e >= N_EDGES) return;
    int d = ei[N_EDGES + e];
    int pos = atomicAdd(&cursor[d], 1);
    int slot = offsets[d] + pos;
    esrc[slot] = ei[e];
    eatt[slot] = eattr[e];
}

// ---------- gather-mean (bf16 in, bf16 out, fused normalize, 4x ILP) ----------
__global__ __launch_bounds__(256) void gather_kernel(
    const unsigned short* __restrict__ zb, const int* __restrict__ offsets,
    const int* __restrict__ esrc, const float* __restrict__ eatt,
    unsigned short* __restrict__ segb)
{
    const int w = threadIdx.x >> 6, lane = threadIdx.x & 63;
    const int n = blockIdx.x * 4 + w;
    if (n >= N_NODES) return;
    const int beg = offsets[n], end = offsets[n + 1], deg = end - beg;

    float ax = 0.f, ay = 0.f;                  // lane owns channels lane*2, lane*2+1
    int i = beg;
    for (; i + 4 <= end; i += 4) {
        int s0 = esrc[i], s1 = esrc[i + 1], s2 = esrc[i + 2], s3 = esrc[i + 3];
        unsigned u0 = *(const unsigned*)(zb + (size_t)s0 * C_IN + lane * 2);
        unsigned u1 = *(const unsigned*)(zb + (size_t)s1 * C_IN + lane * 2);
        unsigned u2 = *(const unsigned*)(zb + (size_t)s2 * C_IN + lane * 2);
        unsigned u3 = *(const unsigned*)(zb + (size_t)s3 * C_IN + lane * 2);
        ax += __uint_as_float(u0 << 16) + __uint_as_float(u1 << 16)
            + __uint_as_float(u2 << 16) + __uint_as_float(u3 << 16);
        ay += __uint_as_float(u0 & 0xffff0000u) + __uint_as_float(u1 & 0xffff0000u)
            + __uint_as_float(u2 & 0xffff0000u) + __uint_as_float(u3 & 0xffff0000u);
    }
    for (; i < end; ++i) {
        int s = esrc[i];
        unsigned u = *(const unsigned*)(zb + (size_t)s * C_IN + lane * 2);
        ax += __uint_as_float(u << 16);
        ay += __uint_as_float(u & 0xffff0000u);
    }
    float asum = 0.f;
    for (int j = beg + lane; j < end; j += 64) asum += eatt[j];
    #pragma unroll
    for (int off = 1; off < 64; off <<= 1) asum += __shfl_xor(asum, off, 64);

    const float inv = (deg > 0) ? 1.0f / (float)deg : 0.0f;
    unsigned short* segn = segb + (size_t)n * SEGB_STRIDE;
    ushort2 o; o.x = f2bf(ax * inv); o.y = f2bf(ay * inv);
    *(ushort2*)(segn + lane * 2) = o;
    if (lane < 16) {
        ushort2 p; p.x = (lane == 0) ? f2bf(asum * inv) : 0; p.y = 0;
        *(ushort2*)(segn + 128 + lane * 2) = p;   // attr @128, zeros 129..159
    }
}

// ---------- edge MLP: bf16 MFMA, 512 thr / 8 waves, 32-col N-slice per wave ----------
// Register diet: bfr[8][2]=64 VGPR + acc[4][2]=32 AGPR per wave -> 4 waves/SIMD,
// LDS ~36KB -> 4 blocks/CU (vs round-5: 180 regs/wave -> 2 blocks/CU).
__global__ __launch_bounds__(512) void edge_mfma_kernel(
    const unsigned short* __restrict__ zb, const int* __restrict__ ei,
    const unsigned short* __restrict__ Bpack,
    const float* __restrict__ be1, const float* __restrict__ We2,
    const float* __restrict__ be2, float* __restrict__ edge_out)
{
    __shared__ __align__(16) unsigned short s_a[64][264];
    __shared__ float s_red[8][64];
    const int tid  = threadIdx.x;
    const int lane = tid & 63, w = tid >> 6;      // w 0..7
    const long long e0 = (long long)blockIdx.x * 64;

    // B frags: wave w owns n-cols [w*32, w*32+32)
    bf16x8 bfr[8][2];
    {
        const bf16x8* bp = (const bf16x8*)Bpack;
        #pragma unroll
        for (int ks = 0; ks < 8; ++ks)
            #pragma unroll
            for (int nt = 0; nt < 2; ++nt)
                bfr[ks][nt] = bp[(ks * 16 + (w * 2 + nt)) * 64 + lane];
    }

    // Stage A: 128 half-rows x 256B; 512 threads x 16B x 4 iters.
    {
        const int l16 = tid & 15;
        #pragma unroll
        for (int it = 0; it < 4; ++it) {
            int hr   = it * 32 + (tid >> 4);      // 0..127
            int e    = (int)(e0 + (hr >> 1));
            int half = hr & 1;
            int node = half ? ei[N_EDGES + e] : ei[e];
            bf16x8 v = *(const bf16x8*)(zb + (size_t)node * C_IN + l16 * 8);
            *(bf16x8*)&s_a[hr >> 1][half * 128 + l16 * 8] = v;
        }
    }
    __syncthreads();

    f32x4 acc[4][2];
    #pragma unroll
    for (int mt = 0; mt < 4; ++mt)
        #pragma unroll
        for (int nt = 0; nt < 2; ++nt)
            acc[mt][nt] = (f32x4){0.f, 0.f, 0.f, 0.f};

    const int m16 = lane & 15, quad = lane >> 4;
    #pragma unroll
    for (int ks = 0; ks < 8; ++ks) {
        #pragma unroll
        for (int mt = 0; mt < 4; ++mt) {
            bf16x8 a = *(const bf16x8*)&s_a[mt * 16 + m16][ks * 32 + quad * 8];
            #pragma unroll
            for (int nt = 0; nt < 2; ++nt)
                acc[mt][nt] = __builtin_amdgcn_mfma_f32_16x16x32_bf16(
                    a, bfr[ks][nt], acc[mt][nt], 0, 0, 0);
        }
    }

    // Epilogue: relu(acc + be1) dot We2 over this wave's 32 cols.
    float esum[4][4];
    #pragma unroll
    for (int mt = 0; mt < 4; ++mt)
        #pragma unroll
        for (int r = 0; r < 4; ++r) esum[mt][r] = 0.f;

    #pragma unroll
    for (int nt = 0; nt < 2; ++nt) {
        int n = w * 32 + nt * 16 + m16;
        float b1 = be1[n], w2 = We2[n];
        #pragma unroll
        for (int mt = 0; mt < 4; ++mt)
            #pragma unroll
            for (int r = 0; r < 4; ++r) {
                float h = fmaxf(acc[mt][nt][r] + b1, 0.f);
                esum[mt][r] += h * w2;
            }
    }
    #pragma unroll
    for (int off = 1; off <= 8; off <<= 1)
        #pragma unroll
        for (int mt = 0; mt < 4; ++mt)
            #pragma unroll
            for (int r = 0; r < 4; ++r)
                esum[mt][r] += __shfl_xor(esum[mt][r], off, 64);
    if (m16 == 0) {
        #pragma unroll
        for (int mt = 0; mt < 4; ++mt)
            #pragma unroll
            for (int r = 0; r < 4; ++r)
                s_red[w][mt * 16 + quad * 4 + r] = esum[mt][r];
    }
    __syncthreads();
    if (tid < 64) {
        float r = be2[0];
        #pragma unroll
        for (int ww = 0; ww < 8; ++ww) r += s_red[ww][tid];
        edge_out[e0 + tid] = r;
    }
}

// ---------- node MLP: bf16 MFMA, both layers, h via LDS round-trip ----------
__global__ __launch_bounds__(256, 2) void node_mfma_kernel(
    const unsigned short* __restrict__ segb, const unsigned short* __restrict__ Wa1b,
    const float* __restrict__ ba1, const unsigned short* __restrict__ Wa2b,
    const float* __restrict__ ba2, float* __restrict__ x_out)
{
    __shared__ __align__(16) unsigned short s_a[64][168];
    __shared__ __align__(16) unsigned short s_h[64][264];
    const int tid  = threadIdx.x;
    const int lane = tid & 63, w = tid >> 6;
    const int m16 = lane & 15, quad = lane >> 4;
    const int n0 = blockIdx.x * 64;

    {
        const unsigned short* src = segb + (size_t)n0 * SEGB_STRIDE;
        #pragma unroll
        for (int i = 0; i < 5; ++i) {
            int c = tid + i * 256;
            int row = c / 20, col = c - row * 20;
            *(uint4*)&s_a[row][col * 8] = *(const uint4*)(src + c * 8);
        }
    }

    bf16x8 bfr1[5][4];
    {
        const bf16x8* bp = (const bf16x8*)Wa1b;
        #pragma unroll
        for (int ks = 0; ks < 5; ++ks)
            #pragma unroll
            for (int nt = 0; nt < 4; ++nt)
                bfr1[ks][nt] = bp[(ks * 16 + (w * 4 + nt)) * 64 + lane];
    }
    __syncthreads();

    f32x4 acc1[4][4];
    #pragma unroll
    for (int mt = 0; mt < 4; ++mt)
        #pragma unroll
        for (int nt = 0; nt < 4; ++nt)
            acc1[mt][nt] = (f32x4){0.f, 0.f, 0.f, 0.f};

    #pragma unroll
    for (int ks = 0; ks < 5; ++ks) {
        #pragma unroll
        for (int mt = 0; mt < 4; ++mt) {
            bf16x8 a = *(const bf16x8*)&s_a[mt * 16 + m16][ks * 32 + quad * 8];
            #pragma unroll
            for (int nt = 0; nt < 4; ++nt)
                acc1[mt][nt] = __builtin_amdgcn_mfma_f32_16x16x32_bf16(
                    a, bfr1[ks][nt], acc1[mt][nt], 0, 0, 0);
        }
    }

    #pragma unroll
    for (int nt = 0; nt < 4; ++nt) {
        const int chan = w * 64 + nt * 16 + m16;
        const float b1 = ba1[chan];
        #pragma unroll
        for (int mt = 0; mt < 4; ++mt)
            #pragma unroll
            for (int r = 0; r < 4; ++r) {
                const int node = mt * 16 + quad * 4 + r;
                s_h[node][chan] = f2bf(fmaxf(acc1[mt][nt][r] + b1, 0.f));
            }
    }

    bf16x8 bfr2[8][2];
    {
        const bf16x8* bp = (const bf16x8*)Wa2b;
        #pragma unroll
        for (int ks = 0; ks < 8; ++ks)
            #pragma unroll
            for (int nt = 0; nt < 2; ++nt)
                bfr2[ks][nt] = bp[(ks * 8 + (w * 2 + nt)) * 64 + lane];
    }
    __syncthreads();

    f32x4 acc2[4][2];
    #pragma unroll
    for (int mt = 0; mt < 4; ++mt)
        #pragma unroll
        for (int nt = 0; nt < 2; ++nt)
            acc2[mt][nt] = (f32x4){0.f, 0.f, 0.f, 0.f};

    #pragma unroll
    for (int ks = 0; ks < 8; ++ks) {
        #pragma unroll
        for (int mt = 0; mt < 4; ++mt) {
            bf16x8 a = *(const bf16x8*)&s_h[mt * 16 + m16][ks * 32 + quad * 8];
            #pragma unroll
            for (int nt = 0; nt < 2; ++nt)
                acc2[mt][nt] = __builtin_amdgcn_mfma_f32_16x16x32_bf16(
                    a, bfr2[ks][nt], acc2[mt][nt], 0, 0, 0);
        }
    }

    #pragma unroll
    for (int nt = 0; nt < 2; ++nt) {
        const int j = w * 32 + nt * 16 + m16;
        const float b2 = ba2[j];
        #pragma unroll
        for (int mt = 0; mt < 4; ++mt)
            #pragma unroll
            for (int r = 0; r < 4; ++r) {
                const int node = n0 + mt * 16 + quad * 4 + r;
                if (node < N_NODES)
                    x_out[(size_t)node * C_OUT + j] = acc2[mt][nt][r] + b2;
            }
    }
}

// ---------- launch ----------
// ws layout (bytes):
//   segb    16,015,360   (50048 rows x 160 bf16)
//   zb      12,800,000
//   Bpack      131,072
//   Wa1b        81,920
//   Wa2b        65,536
//   cnt        200,704   (50176 ints, zero-padded for int4 scan)
//   cursor     200,704
//   offsets    200,064
//   esrc     3,200,000
//   eatt     3,200,000    => ~36.1 MB

extern "C" void kernel_launch(void* const* d_in, const int* in_sizes, int n_in,
                              void* d_out, int out_size, void* d_ws, size_t ws_size,
                              hipStream_t stream) {
    const float* z     = (const float*)d_in[0];
    const int*   ei    = (const int*)d_in[1];     // int32 per harness contract
    const float* eattr = (const float*)d_in[2];
    const float* Wa1   = (const float*)d_in[3];
    const float* ba1   = (const float*)d_in[4];
    const float* Wa2   = (const float*)d_in[5];
    const float* ba2   = (const float*)d_in[6];
    const float* We1   = (const float*)d_in[7];
    const float* be1   = (const float*)d_in[8];
    const float* We2   = (const float*)d_in[9];
    const float* be2   = (const float*)d_in[10];

    float* x_out    = (float*)d_out;
    float* edge_out = x_out + (size_t)N_NODES * C_OUT;

    char* wsb = (char*)d_ws;
    size_t off = 0;
    unsigned short* segb    = (unsigned short*)(wsb + off); off += 16015360;
    unsigned short* zb      = (unsigned short*)(wsb + off); off += 12800000;
    unsigned short* Bpack   = (unsigned short*)(wsb + off); off += 131072;
    unsigned short* Wa1b    = (unsigned short*)(wsb + off); off += 81920;
    unsigned short* Wa2b    = (unsigned short*)(wsb + off); off += 65536;
    int*            cnt     = (int*)(wsb + off);            off += 200704;
    int*            cursor  = (int*)(wsb + off);            off += 200704;
    int*            offsets = (int*)(wsb + off);            off += 200064;
    int*            esrc    = (int*)(wsb + off);            off += 3200000;
    float*          eatt    = (float*)(wsb + off);          off += 3200000;

    hipMemsetAsync(cnt, 0, 2 * 200704, stream);   // cnt + cursor (adjacent)

    cast_z<<<(N_NODES * C_IN / 4 + 255) / 256, 256, 0, stream>>>(z, zb);
    prep_bpack<<<32, 256, 0, stream>>>(We1, Bpack);
    prep_wa1b<<<20, 256, 0, stream>>>(Wa1, Wa1b);
    prep_wa2b<<<16, 256, 0, stream>>>(Wa2, Wa2b);

    hist_kernel<<<(N_EDGES + 255) / 256, 256, 0, stream>>>(ei, cnt);
    scan_kernel<<<1, 256, 0, stream>>>(cnt, offsets);
    fill_kernel<<<(N_EDGES + 255) / 256, 256, 0, stream>>>(ei, eattr, offsets, cursor,
                                                           esrc, eatt);

    edge_mfma_kernel<<<N_EDGES / 64, 512, 0, stream>>>(zb, ei, Bpack, be1, We2, be2,
                                                       edge_out);

    gather_kernel<<<(N_NODES + 3) / 4, 256, 0, stream>>>(zb, offsets, esrc, eatt, segb);
    node_mfma_kernel<<<(N_NODES + 63) / 64, 256, 0, stream>>>(segb, Wa1b, ba1, Wa2b,
                                                              ba2, x_out);
}

// Round 7
// 472.742 us; speedup vs baseline: 5.6246x; 1.0341x over previous
//
#include <hip/hip_runtime.h>

#define N_NODES 50000
#define N_EDGES 800000
#define C_IN    128
#define C_HID   256
#define C_OUT   128
#define SEGB_STRIDE 160   // bf16: [z mean 0..127 | attr 128 | zeros 129..159]

typedef __bf16 bf16x8 __attribute__((ext_vector_type(8)));
typedef float  f32x4  __attribute__((ext_vector_type(4)));

__device__ __forceinline__ unsigned short f2bf(float x) {
    unsigned u = __float_as_uint(x);
    u = (u + 0x7FFF + ((u >> 16) & 1)) >> 16;   // RNE
    return (unsigned short)u;
}

// ---------- prep kernels ----------

__global__ void cast_z(const float* __restrict__ z, unsigned short* __restrict__ zb) {
    int t = blockIdx.x * 256 + threadIdx.x;
    if (t >= N_NODES * C_IN / 4) return;
    float4 v = ((const float4*)z)[t];
    ushort4 o;
    o.x = f2bf(v.x); o.y = f2bf(v.y); o.z = f2bf(v.z); o.w = f2bf(v.w);
    ((ushort4*)zb)[t] = o;
}

// We1 [256k][256n] -> bf16 B-frag order (edge layer1), 8 ks x 16 nt
__global__ void prep_bpack(const float* __restrict__ We1, unsigned short* __restrict__ Bpack) {
    int t = blockIdx.x * 256 + threadIdx.x;
    if (t >= 8 * 16 * 64) return;
    int lane = t & 63, nt = (t >> 6) & 15, ks = t >> 10;
    int n  = nt * 16 + (lane & 15);
    int kb = ks * 32 + (lane >> 4) * 8;
    #pragma unroll
    for (int j = 0; j < 8; ++j)
        Bpack[t * 8 + j] = f2bf(We1[(kb + j) * C_HID + n]);
}

// Wa1 [129k][256n] -> bf16 B-frags for node layer1 with segb column order.
__global__ void prep_wa1b(const float* __restrict__ Wa1, unsigned short* __restrict__ Wa1b) {
    int t = blockIdx.x * 256 + threadIdx.x;
    if (t >= 5 * 16 * 64) return;
    int lane = t & 63, nt = (t >> 6) & 15, ks = t >> 10;      // ks 0..4
    int n = nt * 16 + (lane & 15);
    #pragma unroll
    for (int j = 0; j < 8; ++j) {
        int k = ks * 32 + (lane >> 4) * 8 + j;
        float v = 0.f;
        if (k < 128)       v = Wa1[(k + 1) * C_HID + n];
        else if (k == 128) v = Wa1[0 * C_HID + n];
        Wa1b[t * 8 + j] = f2bf(v);
    }
}

// Wa2 [256k][128n] -> bf16 B-frags (node layer2), 8 ks x 8 nt
__global__ void prep_wa2b(const float* __restrict__ Wa2, unsigned short* __restrict__ Wa2b) {
    int t = blockIdx.x * 256 + threadIdx.x;
    if (t >= 8 * 8 * 64) return;
    int lane = t & 63, nt = (t >> 6) & 7, ks = t >> 9;        // ks 0..7
    int n  = nt * 16 + (lane & 15);
    int kb = ks * 32 + (lane >> 4) * 8;
    #pragma unroll
    for (int j = 0; j < 8; ++j)
        Wa2b[t * 8 + j] = f2bf(Wa2[(kb + j) * C_OUT + n]);
}

// ---------- CSR build ----------

__global__ void hist_kernel(const int* __restrict__ ei, int* __restrict__ cnt) {
    int e = blockIdx.x * 256 + threadIdx.x;
    if (e < N_EDGES) atomicAdd(&cnt[ei[N_EDGES + e]], 1);
}

// cnt zero-padded to 50176 ints so int4 reads need no bounds checks.
__global__ __launch_bounds__(256) void scan_kernel(const int* __restrict__ cnt,
                                                   int* __restrict__ offsets) {
    const int tid = threadIdx.x;
    const int per = 196;                        // 49 int4
    const int base = tid * per;
    const int4* c4 = (const int4*)(cnt + base);
    int sum = 0;
    #pragma unroll 7
    for (int i = 0; i < 49; ++i) {
        int4 v = c4[i];
        sum += v.x + v.y + v.z + v.w;
    }
    const int lane = tid & 63, w = tid >> 6;
    int v = sum;
    #pragma unroll
    for (int off = 1; off < 64; off <<= 1) {
        int t = __shfl_up(v, off, 64);
        if (lane >= off) v += t;
    }
    __shared__ int s_w[4];
    if (lane == 63) s_w[w] = v;
    __syncthreads();
    int wbase = 0;
    for (int i = 0; i < w; ++i) wbase += s_w[i];
    int run = wbase + v - sum;
    for (int i = 0; i < per; ++i) {
        int b = base + i;
        if (b < N_NODES) { offsets[b] = run; run += cnt[b]; }
    }
    if (tid == 255) offsets[N_NODES] = run;
}

// Also emits edst[slot] and perm[slot] so the edge kernel can run in CSR order.
__global__ void fill_kernel(const int* __restrict__ ei, const float* __restrict__ eattr,
                            const int* __restrict__ offsets, int* __restrict__ cursor,
                            int* __restrict__ esrc, int* __restrict__ edst,
                            int* __restrict__ perm, float* __restrict__ eatt) {
    int e = blockIdx.x * 256 + threadIdx.x;
    if (e >= N_EDGES) return;
    int d = ei[N_EDGES + e];
    int pos = atomicAdd(&cursor[d], 1);
    int slot = offsets[d] + pos;
    esrc[slot] = ei[e];
    edst[slot] = d;
    perm[slot] = e;
    eatt[slot] = eattr[e];
}

// ---------- gather-mean (bf16 in, bf16 out, fused normalize, 4x ILP) ----------
__global__ __launch_bounds__(256) void gather_kernel(
    const unsigned short* __restrict__ zb, const int* __restrict__ offsets,
    const int* __restrict__ esrc, const float* __restrict__ eatt,
    unsigned short* __restrict__ segb)
{
    const int w = threadIdx.x >> 6, lane = threadIdx.x & 63;
    const int n = blockIdx.x * 4 + w;
    if (n >= N_NODES) return;
    const int beg = offsets[n], end = offsets[n + 1], deg = end - beg;

    float ax = 0.f, ay = 0.f;                  // lane owns channels lane*2, lane*2+1
    int i = beg;
    for (; i + 4 <= end; i += 4) {
        int s0 = esrc[i], s1 = esrc[i + 1], s2 = esrc[i + 2], s3 = esrc[i + 3];
        unsigned u0 = *(const unsigned*)(zb + (size_t)s0 * C_IN + lane * 2);
        unsigned u1 = *(const unsigned*)(zb + (size_t)s1 * C_IN + lane * 2);
        unsigned u2 = *(const unsigned*)(zb + (size_t)s2 * C_IN + lane * 2);
        unsigned u3 = *(const unsigned*)(zb + (size_t)s3 * C_IN + lane * 2);
        ax += __uint_as_float(u0 << 16) + __uint_as_float(u1 << 16)
            + __uint_as_float(u2 << 16) + __uint_as_float(u3 << 16);
        ay += __uint_as_float(u0 & 0xffff0000u) + __uint_as_float(u1 & 0xffff0000u)
            + __uint_as_float(u2 & 0xffff0000u) + __uint_as_float(u3 & 0xffff0000u);
    }
    for (; i < end; ++i) {
        int s = esrc[i];
        unsigned u = *(const unsigned*)(zb + (size_t)s * C_IN + lane * 2);
        ax += __uint_as_float(u << 16);
        ay += __uint_as_float(u & 0xffff0000u);
    }
    float asum = 0.f;
    for (int j = beg + lane; j < end; j += 64) asum += eatt[j];
    #pragma unroll
    for (int off = 1; off < 64; off <<= 1) asum += __shfl_xor(asum, off, 64);

    const float inv = (deg > 0) ? 1.0f / (float)deg : 0.0f;
    unsigned short* segn = segb + (size_t)n * SEGB_STRIDE;
    ushort2 o; o.x = f2bf(ax * inv); o.y = f2bf(ay * inv);
    *(ushort2*)(segn + lane * 2) = o;
    if (lane < 16) {
        ushort2 p; p.x = (lane == 0) ? f2bf(asum * inv) : 0; p.y = 0;
        *(ushort2*)(segn + 128 + lane * 2) = p;   // attr @128, zeros 129..159
    }
}

// ---------- edge MLP: bf16 MFMA in CSR order (dst rows L1/L2-local) ----------
// Block = 64 CSR slots. Consecutive slots share dst (avg deg 16) -> dst half of
// staging hits cache; only src rows are random. Output scattered via perm.
__global__ __launch_bounds__(512) void edge_mfma_kernel(
    const unsigned short* __restrict__ zb, const int* __restrict__ esrc,
    const int* __restrict__ edst, const int* __restrict__ perm,
    const unsigned short* __restrict__ Bpack,
    const float* __restrict__ be1, const float* __restrict__ We2,
    const float* __restrict__ be2, float* __restrict__ edge_out)
{
    __shared__ __align__(16) unsigned short s_a[64][264];
    __shared__ float s_red[8][64];
    const int tid  = threadIdx.x;
    const int lane = tid & 63, w = tid >> 6;      // w 0..7
    const int s0 = blockIdx.x * 64;

    // B frags: wave w owns n-cols [w*32, w*32+32)
    bf16x8 bfr[8][2];
    {
        const bf16x8* bp = (const bf16x8*)Bpack;
        #pragma unroll
        for (int ks = 0; ks < 8; ++ks)
            #pragma unroll
            for (int nt = 0; nt < 2; ++nt)
                bfr[ks][nt] = bp[(ks * 16 + (w * 2 + nt)) * 64 + lane];
    }

    // Stage A: 128 half-rows x 256B; 512 threads x 16B x 4 iters.
    {
        const int l16 = tid & 15;
        #pragma unroll
        for (int it = 0; it < 4; ++it) {
            int hr   = it * 32 + (tid >> 4);      // 0..127
            int slot = s0 + (hr >> 1);
            int half = hr & 1;
            int node = half ? edst[slot] : esrc[slot];
            bf16x8 v = *(const bf16x8*)(zb + (size_t)node * C_IN + l16 * 8);
            *(bf16x8*)&s_a[hr >> 1][half * 128 + l16 * 8] = v;
        }
    }
    __syncthreads();

    f32x4 acc[4][2];
    #pragma unroll
    for (int mt = 0; mt < 4; ++mt)
        #pragma unroll
        for (int nt = 0; nt < 2; ++nt)
            acc[mt][nt] = (f32x4){0.f, 0.f, 0.f, 0.f};

    const int m16 = lane & 15, quad = lane >> 4;
    #pragma unroll
    for (int ks = 0; ks < 8; ++ks) {
        #pragma unroll
        for (int mt = 0; mt < 4; ++mt) {
            bf16x8 a = *(const bf16x8*)&s_a[mt * 16 + m16][ks * 32 + quad * 8];
            #pragma unroll
            for (int nt = 0; nt < 2; ++nt)
                acc[mt][nt] = __builtin_amdgcn_mfma_f32_16x16x32_bf16(
                    a, bfr[ks][nt], acc[mt][nt], 0, 0, 0);
        }
    }

    // Epilogue: relu(acc + be1) dot We2 over this wave's 32 cols.
    float esum[4][4];
    #pragma unroll
    for (int mt = 0; mt < 4; ++mt)
        #pragma unroll
        for (int r = 0; r < 4; ++r) esum[mt][r] = 0.f;

    #pragma unroll
    for (int nt = 0; nt < 2; ++nt) {
        int n = w * 32 + nt * 16 + m16;
        float b1 = be1[n], w2 = We2[n];
        #pragma unroll
        for (int mt = 0; mt < 4; ++mt)
            #pragma unroll
            for (int r = 0; r < 4; ++r) {
                float h = fmaxf(acc[mt][nt][r] + b1, 0.f);
                esum[mt][r] += h * w2;
            }
    }
    #pragma unroll
    for (int off = 1; off <= 8; off <<= 1)
        #pragma unroll
        for (int mt = 0; mt < 4; ++mt)
            #pragma unroll
            for (int r = 0; r < 4; ++r)
                esum[mt][r] += __shfl_xor(esum[mt][r], off, 64);
    if (m16 == 0) {
        #pragma unroll
        for (int mt = 0; mt < 4; ++mt)
            #pragma unroll
            for (int r = 0; r < 4; ++r)
                s_red[w][mt * 16 + quad * 4 + r] = esum[mt][r];
    }
    __syncthreads();
    if (tid < 64) {
        float r = be2[0];
        #pragma unroll
        for (int ww = 0; ww < 8; ++ww) r += s_red[ww][tid];
        edge_out[perm[s0 + tid]] = r;             // scatter back to original edge order
    }
}

// ---------- node MLP: bf16 MFMA, both layers, h via LDS round-trip ----------
__global__ __launch_bounds__(256, 2) void node_mfma_kernel(
    const unsigned short* __restrict__ segb, const unsigned short* __restrict__ Wa1b,
    const float* __restrict__ ba1, const unsigned short* __restrict__ Wa2b,
    const float* __restrict__ ba2, float* __restrict__ x_out)
{
    __shared__ __align__(16) unsigned short s_a[64][168];
    __shared__ __align__(16) unsigned short s_h[64][264];
    const int tid  = threadIdx.x;
    const int lane = tid & 63, w = tid >> 6;
    const int m16 = lane & 15, quad = lane >> 4;
    const int n0 = blockIdx.x * 64;

    {
        const unsigned short* src = segb + (size_t)n0 * SEGB_STRIDE;
        #pragma unroll
        for (int i = 0; i < 5; ++i) {
            int c = tid + i * 256;
            int row = c / 20, col = c - row * 20;
            *(uint4*)&s_a[row][col * 8] = *(const uint4*)(src + c * 8);
        }
    }

    bf16x8 bfr1[5][4];
    {
        const bf16x8* bp = (const bf16x8*)Wa1b;
        #pragma unroll
        for (int ks = 0; ks < 5; ++ks)
            #pragma unroll
            for (int nt = 0; nt < 4; ++nt)
                bfr1[ks][nt] = bp[(ks * 16 + (w * 4 + nt)) * 64 + lane];
    }
    __syncthreads();

    f32x4 acc1[4][4];
    #pragma unroll
    for (int mt = 0; mt < 4; ++mt)
        #pragma unroll
        for (int nt = 0; nt < 4; ++nt)
            acc1[mt][nt] = (f32x4){0.f, 0.f, 0.f, 0.f};

    #pragma unroll
    for (int ks = 0; ks < 5; ++ks) {
        #pragma unroll
        for (int mt = 0; mt < 4; ++mt) {
            bf16x8 a = *(const bf16x8*)&s_a[mt * 16 + m16][ks * 32 + quad * 8];
            #pragma unroll
            for (int nt = 0; nt < 4; ++nt)
                acc1[mt][nt] = __builtin_amdgcn_mfma_f32_16x16x32_bf16(
                    a, bfr1[ks][nt], acc1[mt][nt], 0, 0, 0);
        }
    }

    #pragma unroll
    for (int nt = 0; nt < 4; ++nt) {
        const int chan = w * 64 + nt * 16 + m16;
        const float b1 = ba1[chan];
        #pragma unroll
        for (int mt = 0; mt < 4; ++mt)
            #pragma unroll
            for (int r = 0; r < 4; ++r) {
                const int node = mt * 16 + quad * 4 + r;
                s_h[node][chan] = f2bf(fmaxf(acc1[mt][nt][r] + b1, 0.f));
            }
    }

    bf16x8 bfr2[8][2];
    {
        const bf16x8* bp = (const bf16x8*)Wa2b;
        #pragma unroll
        for (int ks = 0; ks < 8; ++ks)
            #pragma unroll
            for (int nt = 0; nt < 2; ++nt)
                bfr2[ks][nt] = bp[(ks * 8 + (w * 2 + nt)) * 64 + lane];
    }
    __syncthreads();

    f32x4 acc2[4][2];
    #pragma unroll
    for (int mt = 0; mt < 4; ++mt)
        #pragma unroll
        for (int nt = 0; nt < 2; ++nt)
            acc2[mt][nt] = (f32x4){0.f, 0.f, 0.f, 0.f};

    #pragma unroll
    for (int ks = 0; ks < 8; ++ks) {
        #pragma unroll
        for (int mt = 0; mt < 4; ++mt) {
            bf16x8 a = *(const bf16x8*)&s_h[mt * 16 + m16][ks * 32 + quad * 8];
            #pragma unroll
            for (int nt = 0; nt < 2; ++nt)
                acc2[mt][nt] = __builtin_amdgcn_mfma_f32_16x16x32_bf16(
                    a, bfr2[ks][nt], acc2[mt][nt], 0, 0, 0);
        }
    }

    #pragma unroll
    for (int nt = 0; nt < 2; ++nt) {
        const int j = w * 32 + nt * 16 + m16;
        const float b2 = ba2[j];
        #pragma unroll
        for (int mt = 0; mt < 4; ++mt)
            #pragma unroll
            for (int r = 0; r < 4; ++r) {
                const int node = n0 + mt * 16 + quad * 4 + r;
                if (node < N_NODES)
                    x_out[(size_t)node * C_OUT + j] = acc2[mt][nt][r] + b2;
            }
    }
}

// ---------- launch ----------
// ws layout (bytes):
//   segb    16,015,360   (50048 rows x 160 bf16)
//   zb      12,800,000
//   Bpack      131,072
//   Wa1b        81,920
//   Wa2b        65,536
//   cnt        200,704   (50176 ints, zero-padded for int4 scan)
//   cursor     200,704
//   offsets    200,064
//   esrc     3,200,000
//   edst     3,200,000
//   perm     3,200,000
//   eatt     3,200,000    => ~42.5 MB

extern "C" void kernel_launch(void* const* d_in, const int* in_sizes, int n_in,
                              void* d_out, int out_size, void* d_ws, size_t ws_size,
                              hipStream_t stream) {
    const float* z     = (const float*)d_in[0];
    const int*   ei    = (const int*)d_in[1];     // int32 per harness contract
    const float* eattr = (const float*)d_in[2];
    const float* Wa1   = (const float*)d_in[3];
    const float* ba1   = (const float*)d_in[4];
    const float* Wa2   = (const float*)d_in[5];
    const float* ba2   = (const float*)d_in[6];
    const float* We1   = (const float*)d_in[7];
    const float* be1   = (const float*)d_in[8];
    const float* We2   = (const float*)d_in[9];
    const float* be2   = (const float*)d_in[10];

    float* x_out    = (float*)d_out;
    float* edge_out = x_out + (size_t)N_NODES * C_OUT;

    char* wsb = (char*)d_ws;
    size_t off = 0;
    unsigned short* segb    = (unsigned short*)(wsb + off); off += 16015360;
    unsigned short* zb      = (unsigned short*)(wsb + off); off += 12800000;
    unsigned short* Bpack   = (unsigned short*)(wsb + off); off += 131072;
    unsigned short* Wa1b    = (unsigned short*)(wsb + off); off += 81920;
    unsigned short* Wa2b    = (unsigned short*)(wsb + off); off += 65536;
    int*            cnt     = (int*)(wsb + off);            off += 200704;
    int*            cursor  = (int*)(wsb + off);            off += 200704;
    int*            offsets = (int*)(wsb + off);            off += 200064;
    int*            esrc    = (int*)(wsb + off);            off += 3200000;
    int*            edst    = (int*)(wsb + off);            off += 3200000;
    int*            perm    = (int*)(wsb + off);            off += 3200000;
    float*          eatt    = (float*)(wsb + off);          off += 3200000;

    hipMemsetAsync(cnt, 0, 2 * 200704, stream);   // cnt + cursor (adjacent)

    cast_z<<<(N_NODES * C_IN / 4 + 255) / 256, 256, 0, stream>>>(z, zb);
    prep_bpack<<<32, 256, 0, stream>>>(We1, Bpack);
    prep_wa1b<<<20, 256, 0, stream>>>(Wa1, Wa1b);
    prep_wa2b<<<16, 256, 0, stream>>>(Wa2, Wa2b);

    hist_kernel<<<(N_EDGES + 255) / 256, 256, 0, stream>>>(ei, cnt);
    scan_kernel<<<1, 256, 0, stream>>>(cnt, offsets);
    fill_kernel<<<(N_EDGES + 255) / 256, 256, 0, stream>>>(ei, eattr, offsets, cursor,
                                                           esrc, edst, perm, eatt);

    edge_mfma_kernel<<<N_EDGES / 64, 512, 0, stream>>>(zb, esrc, edst, perm, Bpack,
                                                       be1, We2, be2, edge_out);

    gather_kernel<<<(N_NODES + 3) / 4, 256, 0, stream>>>(zb, offsets, esrc, eatt, segb);
    node_mfma_kernel<<<(N_NODES + 63) / 64, 256, 0, stream>>>(segb, Wa1b, ba1, Wa2b,
                                                              ba2, x_out);
}